// Round 2
// baseline (421.981 us; speedup 1.0000x reference)
//
#include <hip/hip_runtime.h>
#include <math.h>

// ---------------------------------------------------------------------------
// Deep4Net, fp32, stage-split kernels with global intermediates (all L2/L3
// resident). conv1+conv2 fused algebraically; pool(elu)=elu(pool).
// All conv weights transposed by k_prep to [i][k][o] (o padded to x4) so the
// inner loop loads one float4 of weights per k (broadcast across lanes).
//
// Workspace layout (float offsets):
#define WCT 0         // 22*10*28  = 6160   Wc^T [c][k][o28]
#define BCP 6160      // 28                 combined bias, padded
#define W2T 6192      // 25*10*52  = 13000  w2^T [i][k][o52]
#define B2P 19192     // 52
#define W3T 19244     // 50*10*100 = 50000  w3^T [i][k][o100]
#define W4T 69244     // 100*10*200= 200000 w4^T [i][k][o200]
#define P1  269248    // 256*25*330 = 2112000
#define P2  2381248   // 256*50*108 = 1382400 (rows padded 107->108 for align)
#define P3  3763648   // 256*100*32 = 819200
#define P4  4582848   // 256*1400   = 358400
// ---------------------------------------------------------------------------

__device__ __forceinline__ float elu1(float v) {
    return v > 0.f ? v : __expf(v) - 1.f;
}
__device__ __forceinline__ float max3(float a, float b, float c) {
    return fmaxf(fmaxf(a, b), c);
}

// ---- K0: weight prep (combine conv1/2, transpose all) ---------------------
__global__ __launch_bounds__(256) void k_prep(
    const float* __restrict__ wt, const float* __restrict__ bt,
    const float* __restrict__ wsp, const float* __restrict__ bsp,
    const float* __restrict__ w2, const float* __restrict__ b2,
    const float* __restrict__ w3, const float* __restrict__ w4,
    float* __restrict__ ws) {
    int idx = blockIdx.x * 256 + threadIdx.x;
    if (idx < 6160) {                       // WCT [c][k][o28]
        int c = idx / 280, r = idx % 280;
        int k = r / 28, o = r % 28;
        float s = 0.f;
        if (o < 25)
            for (int i = 0; i < 25; ++i) s += wt[i * 10 + k] * wsp[(o * 25 + i) * 22 + c];
        ws[WCT + idx] = s;
    } else if (idx < 6188) {                // BCP
        int o = idx - 6160;
        float s = 0.f;
        if (o < 25) {
            s = bsp[o];
            for (int i = 0; i < 25; ++i) {
                float rs = 0.f;
                for (int c = 0; c < 22; ++c) rs += wsp[(o * 25 + i) * 22 + c];
                s += bt[i] * rs;
            }
        }
        ws[BCP + o] = s;
    } else if (idx >= W2T && idx < W2T + 13000) {
        int j = idx - W2T;
        int i = j / 520, r = j % 520, k = r / 52, o = r % 52;
        ws[idx] = (o < 50) ? w2[(o * 25 + i) * 10 + k] : 0.f;
    } else if (idx >= B2P && idx < B2P + 52) {
        int o = idx - B2P;
        ws[idx] = (o < 50) ? b2[o] : 0.f;
    } else if (idx >= W3T && idx < W3T + 50000) {
        int j = idx - W3T;
        int i = j / 1000, r = j % 1000, k = r / 100, o = r % 100;
        ws[idx] = w3[(o * 50 + i) * 10 + k];
    } else if (idx >= W4T && idx < W4T + 200000) {
        int j = idx - W4T;
        int i = j / 2000, r = j % 2000, k = r / 200, o = r % 200;
        ws[idx] = w4[(o * 100 + i) * 10 + k];
    }
}

// ---- K1: combined conv + ELU + pool3 -> p1[b][25][330] --------------------
// thread = (b, og of 4 o's [7 groups, o padded 28], tpg of 2 pooled t [165])
// items = 256*7*165 = 295680 = 1155 blocks exactly
__global__ __launch_bounds__(256) void k_conv12(const float* __restrict__ x,
                                                const float* __restrict__ ws) {
    int item = blockIdx.x * 256 + threadIdx.x;
    int tpg = item % 165;
    int t2 = item / 165;
    int og = t2 % 7, b = t2 / 7;
    int o0 = og * 4;
    int tl = tpg * 6;

    float4 bv = *reinterpret_cast<const float4*>(ws + BCP + o0);
    float acc[4][6];
#pragma unroll
    for (int j = 0; j < 6; ++j) {
        acc[0][j] = bv.x; acc[1][j] = bv.y; acc[2][j] = bv.z; acc[3][j] = bv.w;
    }
    const float* xbase = x + b * 22000 + tl;
    const float* wbase = ws + WCT + o0;
    for (int c = 0; c < 22; ++c) {
        float xv[15];
        const float* xrow = xbase + c * 1000;
        const float2* xp = reinterpret_cast<const float2*>(xrow);
#pragma unroll
        for (int q = 0; q < 7; ++q) { float2 v = xp[q]; xv[2 * q] = v.x; xv[2 * q + 1] = v.y; }
        xv[14] = xrow[14];
        const float* wp = wbase + c * 280;
#pragma unroll
        for (int k = 0; k < 10; ++k) {
            float4 w = *reinterpret_cast<const float4*>(wp + k * 28);
#pragma unroll
            for (int j = 0; j < 6; ++j) {
                float xx = xv[j + k];
                acc[0][j] = fmaf(xx, w.x, acc[0][j]);
                acc[1][j] = fmaf(xx, w.y, acc[1][j]);
                acc[2][j] = fmaf(xx, w.z, acc[2][j]);
                acc[3][j] = fmaf(xx, w.w, acc[3][j]);
            }
        }
    }
    float* p1 = const_cast<float*>(ws) + P1;
    int tp0 = tpg * 2;
#pragma unroll
    for (int oo = 0; oo < 4; ++oo) {
        int o = o0 + oo;
        if (o < 25) {
            float2 st;
            st.x = elu1(max3(acc[oo][0], acc[oo][1], acc[oo][2]));
            st.y = elu1(max3(acc[oo][3], acc[oo][4], acc[oo][5]));
            *reinterpret_cast<float2*>(p1 + (b * 25 + o) * 330 + tp0) = st;
        }
    }
}

// ---- K2: conv3 + ELU + pool -> p2[b][50][108-padded] ----------------------
// thread = (b, og of 4 [13 groups, o pad 52], tpg of 2 [54]) = 702 blocks
__global__ __launch_bounds__(256) void k_conv3(float* __restrict__ ws) {
    int item = blockIdx.x * 256 + threadIdx.x;
    int tpg = item % 54;
    int t2 = item / 54;
    int og = t2 % 13, b = t2 / 13;
    int o0 = og * 4;
    int tl = tpg * 6;

    float4 bv = *reinterpret_cast<const float4*>(ws + B2P + o0);
    float acc[4][6];
#pragma unroll
    for (int j = 0; j < 6; ++j) {
        acc[0][j] = bv.x; acc[1][j] = bv.y; acc[2][j] = bv.z; acc[3][j] = bv.w;
    }
    const float* p1 = ws + P1;
    const float* wbase = ws + W2T + o0;
    for (int i = 0; i < 25; ++i) {
        float xv[15];
        const float* xrow = p1 + (b * 25 + i) * 330 + tl;
        const float2* xp = reinterpret_cast<const float2*>(xrow);
#pragma unroll
        for (int q = 0; q < 7; ++q) { float2 v = xp[q]; xv[2 * q] = v.x; xv[2 * q + 1] = v.y; }
        xv[14] = xrow[14];
        const float* wp = wbase + i * 520;
#pragma unroll
        for (int k = 0; k < 10; ++k) {
            float4 w = *reinterpret_cast<const float4*>(wp + k * 52);
#pragma unroll
            for (int j = 0; j < 6; ++j) {
                float xx = xv[j + k];
                acc[0][j] = fmaf(xx, w.x, acc[0][j]);
                acc[1][j] = fmaf(xx, w.y, acc[1][j]);
                acc[2][j] = fmaf(xx, w.z, acc[2][j]);
                acc[3][j] = fmaf(xx, w.w, acc[3][j]);
            }
        }
    }
    float* p2 = ws + P2;
    int tp0 = tpg * 2;
#pragma unroll
    for (int oo = 0; oo < 4; ++oo) {
        int o = o0 + oo;
        if (o < 50) {
            float* orow = p2 + (b * 50 + o) * 108;
            orow[tp0] = elu1(max3(acc[oo][0], acc[oo][1], acc[oo][2]));
            if (tp0 + 1 < 107)
                orow[tp0 + 1] = elu1(max3(acc[oo][3], acc[oo][4], acc[oo][5]));
        }
    }
}

// ---- K3: conv4 + ELU + pool -> p3[b][100][32] -----------------------------
// thread = (b, og of 4 [25], tpg of 2 [16]) = 400 blocks
__global__ __launch_bounds__(256) void k_conv4(const float* __restrict__ b3,
                                               float* __restrict__ ws) {
    int item = blockIdx.x * 256 + threadIdx.x;
    int tpg = item % 16;
    int t2 = item / 16;
    int og = t2 % 25, b = t2 / 25;
    int o0 = og * 4;
    int tl = tpg * 6;

    float4 bv = *reinterpret_cast<const float4*>(b3 + o0);
    float acc[4][6];
#pragma unroll
    for (int j = 0; j < 6; ++j) {
        acc[0][j] = bv.x; acc[1][j] = bv.y; acc[2][j] = bv.z; acc[3][j] = bv.w;
    }
    const float* p2 = ws + P2;
    const float* wbase = ws + W3T + o0;
    for (int i = 0; i < 50; ++i) {
        float xv[15];
        const float* xrow = p2 + (b * 50 + i) * 108 + tl;
        const float2* xp = reinterpret_cast<const float2*>(xrow);
#pragma unroll
        for (int q = 0; q < 7; ++q) { float2 v = xp[q]; xv[2 * q] = v.x; xv[2 * q + 1] = v.y; }
        xv[14] = xrow[14];
        const float* wp = wbase + i * 1000;
#pragma unroll
        for (int k = 0; k < 10; ++k) {
            float4 w = *reinterpret_cast<const float4*>(wp + k * 100);
#pragma unroll
            for (int j = 0; j < 6; ++j) {
                float xx = xv[j + k];
                acc[0][j] = fmaf(xx, w.x, acc[0][j]);
                acc[1][j] = fmaf(xx, w.y, acc[1][j]);
                acc[2][j] = fmaf(xx, w.z, acc[2][j]);
                acc[3][j] = fmaf(xx, w.w, acc[3][j]);
            }
        }
    }
    float* p3 = ws + P3;
    int tp0 = tpg * 2;
#pragma unroll
    for (int oo = 0; oo < 4; ++oo) {
        int o = o0 + oo;
        float2 st;
        st.x = elu1(max3(acc[oo][0], acc[oo][1], acc[oo][2]));
        st.y = elu1(max3(acc[oo][3], acc[oo][4], acc[oo][5]));
        *reinterpret_cast<float2*>(p3 + (b * 100 + o) * 32 + tp0) = st;
    }
}

// ---- K4: conv5 + ELU + pool -> p4 feat[b][1400] ---------------------------
// thread = (b, og of 2 [100], isplit [4 x 25i]); quad-lane shfl reduce.
// items = 256*100*4 = 102400 = 400 blocks
__global__ __launch_bounds__(256) void k_conv5(const float* __restrict__ b4,
                                               float* __restrict__ ws) {
    int item = blockIdx.x * 256 + threadIdx.x;
    int is = item & 3;
    int t2 = item >> 2;
    int og = t2 % 100, b = t2 / 100;
    int o0 = og * 2;
    int i0 = is * 25;

    float acc0[21], acc1[21];
#pragma unroll
    for (int j = 0; j < 21; ++j) { acc0[j] = 0.f; acc1[j] = 0.f; }
    const float* p3 = ws + P3;
    const float* wbase = ws + W4T + o0;
    for (int ii = 0; ii < 25; ++ii) {
        int i = i0 + ii;
        float xv[30];
        const float* xrow = p3 + (b * 100 + i) * 32;
        const float4* xp = reinterpret_cast<const float4*>(xrow);
#pragma unroll
        for (int q = 0; q < 7; ++q) {
            float4 v = xp[q];
            xv[4 * q] = v.x; xv[4 * q + 1] = v.y; xv[4 * q + 2] = v.z; xv[4 * q + 3] = v.w;
        }
        { float2 v = *reinterpret_cast<const float2*>(xrow + 28); xv[28] = v.x; xv[29] = v.y; }
        const float* wp = wbase + i * 2000;
#pragma unroll
        for (int k = 0; k < 10; ++k) {
            float2 w = *reinterpret_cast<const float2*>(wp + k * 200);
#pragma unroll
            for (int j = 0; j < 21; ++j) {
                float xx = xv[j + k];
                acc0[j] = fmaf(xx, w.x, acc0[j]);
                acc1[j] = fmaf(xx, w.y, acc1[j]);
            }
        }
    }
#pragma unroll
    for (int j = 0; j < 21; ++j) {
        acc0[j] += __shfl_xor(acc0[j], 1);
        acc0[j] += __shfl_xor(acc0[j], 2);
        acc1[j] += __shfl_xor(acc1[j], 1);
        acc1[j] += __shfl_xor(acc1[j], 2);
    }
    if (is == 0) {
        float* p4 = ws + P4 + b * 1400;
        float bb0 = b4[o0], bb1 = b4[o0 + 1];
#pragma unroll
        for (int tp = 0; tp < 7; ++tp) {
            p4[o0 * 7 + tp] = elu1(max3(acc0[3 * tp], acc0[3 * tp + 1], acc0[3 * tp + 2]) + bb0);
            p4[(o0 + 1) * 7 + tp] = elu1(max3(acc1[3 * tp], acc1[3 * tp + 1], acc1[3 * tp + 2]) + bb1);
        }
    }
}

// ---- K5: per-sample head, one wave per output -----------------------------
__global__ __launch_bounds__(256) void k_head(const float* __restrict__ hW,
                                              const float* __restrict__ hB,
                                              const int* __restrict__ sid,
                                              const float* __restrict__ ws,
                                              float* __restrict__ out) {
    int b = blockIdx.x;
    int tid = threadIdx.x;
    int wave = tid >> 6, lane = tid & 63;
    const float* feat = ws + P4 + b * 1400;
    int sidb = sid[b];
    const float* wrow = hW + (sidb * 4 + wave) * 1400;
    float acc = 0.f;
    for (int f = lane; f < 1400; f += 64) acc += wrow[f] * feat[f];
#pragma unroll
    for (int off = 32; off; off >>= 1) acc += __shfl_down(acc, off);
    if (lane == 0) out[b * 4 + wave] = acc + hB[sidb * 4 + wave];
}

extern "C" void kernel_launch(void* const* d_in, const int* in_sizes, int n_in,
                              void* d_out, int out_size, void* d_ws, size_t ws_size,
                              hipStream_t stream) {
    const float* x   = (const float*)d_in[0];
    const int*   sid = (const int*)d_in[1];
    const float* wt  = (const float*)d_in[2];
    const float* bt  = (const float*)d_in[3];
    const float* wsp = (const float*)d_in[4];
    const float* bsp = (const float*)d_in[5];
    const float* w2  = (const float*)d_in[6];
    const float* b2  = (const float*)d_in[7];
    const float* w3  = (const float*)d_in[8];
    const float* b3  = (const float*)d_in[9];
    const float* w4  = (const float*)d_in[10];
    const float* b4  = (const float*)d_in[11];
    const float* hW  = (const float*)d_in[12];
    const float* hB  = (const float*)d_in[13];
    float* out = (float*)d_out;
    float* ws  = (float*)d_ws;

    k_prep<<<1052, 256, 0, stream>>>(wt, bt, wsp, bsp, w2, b2, w3, w4, ws);
    k_conv12<<<1155, 256, 0, stream>>>(x, ws);
    k_conv3<<<702, 256, 0, stream>>>(ws);
    k_conv4<<<400, 256, 0, stream>>>(b3, ws);
    k_conv5<<<400, 256, 0, stream>>>(b4, ws);
    k_head<<<256, 256, 0, stream>>>(hW, hB, sid, ws, out);
}

// Round 3
// 335.643 us; speedup vs baseline: 1.2572x; 1.2572x over previous
//
#include <hip/hip_runtime.h>
#include <math.h>

// ---------------------------------------------------------------------------
// Deep4Net, fp32. One WAVE per block for all conv kernels: every weight
// address derives from blockIdx only -> scalar (SGPR) loads broadcast via
// the SMEM pipe; v_fma takes the SGPR operand. Lanes carry only x + acc.
// conv1+conv2 fused algebraically; pool(elu)=elu(pool).
//
// Workspace layout (float offsets):
#define WCT 0         // 22*10*28  = 6160   Wc^T [c][k][o28]
#define BCP 6160      // 28
#define W2T 6192      // 25*10*52  = 13000  w2^T [i][k][o52]
#define B2P 19192     // 52
#define W3T 19244     // 50*10*100 = 50000  w3^T [i][k][o100]
#define W4T 69244     // 100*10*200= 200000 w4^T [i][k][o200]
#define P1  269248    // 256*25*330
#define P2  2381248   // 256*50*108 (rows padded 107->108)
#define P3  3763648   // 256*100*32
#define P4  4582848   // 256*1400
// ---------------------------------------------------------------------------

__device__ __forceinline__ float elu1(float v) {
    return v > 0.f ? v : __expf(v) - 1.f;
}
__device__ __forceinline__ float max3(float a, float b, float c) {
    return fmaxf(fmaxf(a, b), c);
}

// ---- K0: weight prep (combine conv1/2, transpose all) ---------------------
__global__ __launch_bounds__(256) void k_prep(
    const float* __restrict__ wt, const float* __restrict__ bt,
    const float* __restrict__ wsp, const float* __restrict__ bsp,
    const float* __restrict__ w2, const float* __restrict__ b2,
    const float* __restrict__ w3, const float* __restrict__ w4,
    float* __restrict__ ws) {
    int idx = blockIdx.x * 256 + threadIdx.x;
    if (idx < 6160) {                       // WCT [c][k][o28]
        int c = idx / 280, r = idx % 280;
        int k = r / 28, o = r % 28;
        float s = 0.f;
        if (o < 25)
            for (int i = 0; i < 25; ++i) s += wt[i * 10 + k] * wsp[(o * 25 + i) * 22 + c];
        ws[WCT + idx] = s;
    } else if (idx < 6188) {                // BCP
        int o = idx - 6160;
        float s = 0.f;
        if (o < 25) {
            s = bsp[o];
            for (int i = 0; i < 25; ++i) {
                float rs = 0.f;
                for (int c = 0; c < 22; ++c) rs += wsp[(o * 25 + i) * 22 + c];
                s += bt[i] * rs;
            }
        }
        ws[BCP + o] = s;
    } else if (idx >= W2T && idx < W2T + 13000) {
        int j = idx - W2T;
        int i = j / 520, r = j % 520, k = r / 52, o = r % 52;
        ws[idx] = (o < 50) ? w2[(o * 25 + i) * 10 + k] : 0.f;
    } else if (idx >= B2P && idx < B2P + 52) {
        int o = idx - B2P;
        ws[idx] = (o < 50) ? b2[o] : 0.f;
    } else if (idx >= W3T && idx < W3T + 50000) {
        int j = idx - W3T;
        int i = j / 1000, r = j % 1000, k = r / 100, o = r % 100;
        ws[idx] = w3[(o * 50 + i) * 10 + k];
    } else if (idx >= W4T && idx < W4T + 200000) {
        int j = idx - W4T;
        int i = j / 2000, r = j % 2000, k = r / 200, o = r % 200;
        ws[idx] = w4[(o * 100 + i) * 10 + k];
    }
}

// ---- K1: combined conv + ELU + pool3 -> p1[b][25][330] --------------------
// 1 wave/block. block = (b, og7, tc3); lanes = tpg (55 active).
__global__ __launch_bounds__(64, 6) void k_conv12(
    const float* __restrict__ x, const float* __restrict__ wct,
    const float* __restrict__ bcp, float* __restrict__ p1) {
    int bw = blockIdx.x;
    int tc = bw % 3, og = (bw / 3) % 7, b = bw / 21;
    int o0 = og * 4;                       // scalar
    int lane = threadIdx.x;
    int tpg = tc * 55 + lane;
    bool act = lane < 55;
    int tpgc = act ? tpg : 164;
    int tl = tpgc * 6;

    float4 bv = *reinterpret_cast<const float4*>(bcp + o0);   // scalar load
    float acc[4][6];
#pragma unroll
    for (int j = 0; j < 6; ++j) {
        acc[0][j] = bv.x; acc[1][j] = bv.y; acc[2][j] = bv.z; acc[3][j] = bv.w;
    }
    const float* xbase = x + b * 22000 + tl;
    for (int c = 0; c < 22; ++c) {
        float xv[15];
        const float* xrow = xbase + c * 1000;
        const float2* xp = reinterpret_cast<const float2*>(xrow);
#pragma unroll
        for (int q = 0; q < 7; ++q) { float2 v = xp[q]; xv[2 * q] = v.x; xv[2 * q + 1] = v.y; }
        xv[14] = xrow[14];
        const float* wp = wct + c * 280 + o0;                 // scalar addr
#pragma unroll
        for (int k = 0; k < 10; ++k) {
            float4 w = *reinterpret_cast<const float4*>(wp + k * 28);  // s_load
#pragma unroll
            for (int j = 0; j < 6; ++j) {
                float xx = xv[j + k];
                acc[0][j] = fmaf(xx, w.x, acc[0][j]);
                acc[1][j] = fmaf(xx, w.y, acc[1][j]);
                acc[2][j] = fmaf(xx, w.z, acc[2][j]);
                acc[3][j] = fmaf(xx, w.w, acc[3][j]);
            }
        }
    }
    if (act) {
        int tp0 = tpg * 2;
#pragma unroll
        for (int oo = 0; oo < 4; ++oo) {
            if (o0 + oo < 25) {
                float2 st;
                st.x = elu1(max3(acc[oo][0], acc[oo][1], acc[oo][2]));
                st.y = elu1(max3(acc[oo][3], acc[oo][4], acc[oo][5]));
                *reinterpret_cast<float2*>(p1 + (b * 25 + o0 + oo) * 330 + tp0) = st;
            }
        }
    }
}

// ---- K2: conv3 + ELU + pool -> p2[b][50][108] -----------------------------
// 1 wave/block. block = (b, og13); lanes = tpg (54 active).
__global__ __launch_bounds__(64, 6) void k_conv3(
    const float* __restrict__ p1, const float* __restrict__ w2t,
    const float* __restrict__ b2p, float* __restrict__ p2) {
    int bw = blockIdx.x;
    int og = bw % 13, b = bw / 13;
    int o0 = og * 4;
    int lane = threadIdx.x;
    bool act = lane < 54;
    int tpg = act ? lane : 53;
    int tl = tpg * 6;

    float4 bv = *reinterpret_cast<const float4*>(b2p + o0);
    float acc[4][6];
#pragma unroll
    for (int j = 0; j < 6; ++j) {
        acc[0][j] = bv.x; acc[1][j] = bv.y; acc[2][j] = bv.z; acc[3][j] = bv.w;
    }
    for (int i = 0; i < 25; ++i) {
        float xv[15];
        const float* xrow = p1 + (b * 25 + i) * 330 + tl;
        const float2* xp = reinterpret_cast<const float2*>(xrow);
#pragma unroll
        for (int q = 0; q < 7; ++q) { float2 v = xp[q]; xv[2 * q] = v.x; xv[2 * q + 1] = v.y; }
        xv[14] = xrow[14];
        const float* wp = w2t + i * 520 + o0;
#pragma unroll
        for (int k = 0; k < 10; ++k) {
            float4 w = *reinterpret_cast<const float4*>(wp + k * 52);
#pragma unroll
            for (int j = 0; j < 6; ++j) {
                float xx = xv[j + k];
                acc[0][j] = fmaf(xx, w.x, acc[0][j]);
                acc[1][j] = fmaf(xx, w.y, acc[1][j]);
                acc[2][j] = fmaf(xx, w.z, acc[2][j]);
                acc[3][j] = fmaf(xx, w.w, acc[3][j]);
            }
        }
    }
    if (act) {
        int tp0 = tpg * 2;
#pragma unroll
        for (int oo = 0; oo < 4; ++oo) {
            int o = o0 + oo;
            if (o < 50) {
                float* orow = p2 + (b * 50 + o) * 108;
                float e0 = elu1(max3(acc[oo][0], acc[oo][1], acc[oo][2]));
                if (tp0 + 1 < 107) {
                    float2 st; st.x = e0;
                    st.y = elu1(max3(acc[oo][3], acc[oo][4], acc[oo][5]));
                    *reinterpret_cast<float2*>(orow + tp0) = st;
                } else {
                    orow[tp0] = e0;
                }
            }
        }
    }
}

// ---- K3: conv4 + ELU + pool -> p3[b][100][32] -----------------------------
// 1 wave/block. block = (bquad, og25); lanes = bsub4 x tpg16.
__global__ __launch_bounds__(64, 6) void k_conv4(
    const float* __restrict__ p2, const float* __restrict__ w3t,
    const float* __restrict__ b3, float* __restrict__ p3) {
    int bw = blockIdx.x;
    int og = bw % 25, bq = bw / 25;
    int o0 = og * 4;
    int lane = threadIdx.x;
    int bsub = lane >> 4, tpg = lane & 15;
    int b = bq * 4 + bsub;
    int tl = tpg * 6;

    float4 bv = *reinterpret_cast<const float4*>(b3 + o0);
    float acc[4][6];
#pragma unroll
    for (int j = 0; j < 6; ++j) {
        acc[0][j] = bv.x; acc[1][j] = bv.y; acc[2][j] = bv.z; acc[3][j] = bv.w;
    }
    for (int i = 0; i < 50; ++i) {
        float xv[15];
        const float* xrow = p2 + (b * 50 + i) * 108 + tl;
        const float2* xp = reinterpret_cast<const float2*>(xrow);
#pragma unroll
        for (int q = 0; q < 7; ++q) { float2 v = xp[q]; xv[2 * q] = v.x; xv[2 * q + 1] = v.y; }
        xv[14] = xrow[14];
        const float* wp = w3t + i * 1000 + o0;
#pragma unroll
        for (int k = 0; k < 10; ++k) {
            float4 w = *reinterpret_cast<const float4*>(wp + k * 100);
#pragma unroll
            for (int j = 0; j < 6; ++j) {
                float xx = xv[j + k];
                acc[0][j] = fmaf(xx, w.x, acc[0][j]);
                acc[1][j] = fmaf(xx, w.y, acc[1][j]);
                acc[2][j] = fmaf(xx, w.z, acc[2][j]);
                acc[3][j] = fmaf(xx, w.w, acc[3][j]);
            }
        }
    }
    int tp0 = tpg * 2;
#pragma unroll
    for (int oo = 0; oo < 4; ++oo) {
        float2 st;
        st.x = elu1(max3(acc[oo][0], acc[oo][1], acc[oo][2]));
        st.y = elu1(max3(acc[oo][3], acc[oo][4], acc[oo][5]));
        *reinterpret_cast<float2*>(p3 + (b * 100 + o0 + oo) * 32 + tp0) = st;
    }
}

// ---- K4: conv5 + ELU + pool -> p4[b][1400] --------------------------------
// 1 wave/block. block = (bg32, opair100); lanes = is8 x bsub8.
// i-split strided by 8 across is; shfl_xor reduce over is; lanes 0-7 store.
__global__ __launch_bounds__(64, 3) void k_conv5(
    const float* __restrict__ p3, const float* __restrict__ w4t,
    const float* __restrict__ b4, float* __restrict__ p4) {
    int bw = blockIdx.x;
    int op = bw % 100, bg = bw / 100;
    int o0 = op * 2;
    int lane = threadIdx.x;
    int is = lane >> 3, bsub = lane & 7;
    int b = bg * 8 + bsub;

    float acc0[21], acc1[21];
#pragma unroll
    for (int j = 0; j < 21; ++j) { acc0[j] = 0.f; acc1[j] = 0.f; }
    for (int ii = 0; ii < 13; ++ii) {
        int i = is + ii * 8;
        if (i < 100) {
            float xv[30];
            const float* xrow = p3 + (b * 100 + i) * 32;
            const float4* xp = reinterpret_cast<const float4*>(xrow);
#pragma unroll
            for (int q = 0; q < 7; ++q) {
                float4 v = xp[q];
                xv[4 * q] = v.x; xv[4 * q + 1] = v.y; xv[4 * q + 2] = v.z; xv[4 * q + 3] = v.w;
            }
            { float2 v = *reinterpret_cast<const float2*>(xrow + 28); xv[28] = v.x; xv[29] = v.y; }
            const float* wp = w4t + i * 2000 + o0;
#pragma unroll
            for (int k = 0; k < 10; ++k) {
                float2 w = *reinterpret_cast<const float2*>(wp + k * 200);
#pragma unroll
                for (int j = 0; j < 21; ++j) {
                    float xx = xv[j + k];
                    acc0[j] = fmaf(xx, w.x, acc0[j]);
                    acc1[j] = fmaf(xx, w.y, acc1[j]);
                }
            }
        }
    }
#pragma unroll
    for (int j = 0; j < 21; ++j) {
        acc0[j] += __shfl_xor(acc0[j], 8);
        acc0[j] += __shfl_xor(acc0[j], 16);
        acc0[j] += __shfl_xor(acc0[j], 32);
        acc1[j] += __shfl_xor(acc1[j], 8);
        acc1[j] += __shfl_xor(acc1[j], 16);
        acc1[j] += __shfl_xor(acc1[j], 32);
    }
    if (is == 0) {
        float bb0 = b4[o0], bb1 = b4[o0 + 1];
        float* pr = p4 + b * 1400;
#pragma unroll
        for (int tp = 0; tp < 7; ++tp) {
            pr[o0 * 7 + tp] = elu1(max3(acc0[3 * tp], acc0[3 * tp + 1], acc0[3 * tp + 2]) + bb0);
            pr[(o0 + 1) * 7 + tp] = elu1(max3(acc1[3 * tp], acc1[3 * tp + 1], acc1[3 * tp + 2]) + bb1);
        }
    }
}

// ---- K5: per-sample head, one wave per output -----------------------------
__global__ __launch_bounds__(256) void k_head(const float* __restrict__ hW,
                                              const float* __restrict__ hB,
                                              const int* __restrict__ sid,
                                              const float* __restrict__ p4,
                                              float* __restrict__ out) {
    int b = blockIdx.x;
    int tid = threadIdx.x;
    int wave = tid >> 6, lane = tid & 63;
    const float* feat = p4 + b * 1400;
    int sidb = sid[b];
    const float* wrow = hW + (sidb * 4 + wave) * 1400;
    float acc = 0.f;
    for (int f = lane; f < 1400; f += 64) acc += wrow[f] * feat[f];
#pragma unroll
    for (int off = 32; off; off >>= 1) acc += __shfl_down(acc, off);
    if (lane == 0) out[b * 4 + wave] = acc + hB[sidb * 4 + wave];
}

extern "C" void kernel_launch(void* const* d_in, const int* in_sizes, int n_in,
                              void* d_out, int out_size, void* d_ws, size_t ws_size,
                              hipStream_t stream) {
    const float* x   = (const float*)d_in[0];
    const int*   sid = (const int*)d_in[1];
    const float* wt  = (const float*)d_in[2];
    const float* bt  = (const float*)d_in[3];
    const float* wsp = (const float*)d_in[4];
    const float* bsp = (const float*)d_in[5];
    const float* w2  = (const float*)d_in[6];
    const float* b2  = (const float*)d_in[7];
    const float* w3  = (const float*)d_in[8];
    const float* b3  = (const float*)d_in[9];
    const float* w4  = (const float*)d_in[10];
    const float* b4  = (const float*)d_in[11];
    const float* hW  = (const float*)d_in[12];
    const float* hB  = (const float*)d_in[13];
    float* out = (float*)d_out;
    float* ws  = (float*)d_ws;

    k_prep<<<1052, 256, 0, stream>>>(wt, bt, wsp, bsp, w2, b2, w3, w4, ws);
    k_conv12<<<5376, 64, 0, stream>>>(x, ws + WCT, ws + BCP, ws + P1);
    k_conv3<<<3328, 64, 0, stream>>>(ws + P1, ws + W2T, ws + B2P, ws + P2);
    k_conv4<<<1600, 64, 0, stream>>>(ws + P2, ws + W3T, b3, ws + P3);
    k_conv5<<<3200, 64, 0, stream>>>(ws + P3, ws + W4T, b4, ws + P4);
    k_head<<<256, 256, 0, stream>>>(hW, hB, sid, ws + P4, out);
}

// Round 4
// 257.284 us; speedup vs baseline: 1.6401x; 1.3046x over previous
//
#include <hip/hip_runtime.h>
#include <math.h>

// ---------------------------------------------------------------------------
// Deep4Net, fp32. conv1+conv2 fused algebraically; pool(elu)=elu(pool).
// conv12/conv3: wave-uniform (scalar) weights, lanes = time positions,
//               per-sample input staged in LDS, 7 og-waves per block.
// conv4/conv5:  lanes = output channel, weights [i][o][k-pad12] so each lane
//               loads its own 48B weight row (coalesced); x staged in LDS and
//               read as same-address broadcast; i split 4-way across waves
//               with LDS partial reduce. Per-lane live set <= ~50 VGPR.
//
// Workspace (float offsets):
#define WCT 0          // 22*10*28  Wc^T [c][k][o28]
#define BCP 6160       // 28
#define W2T 6192       // 25*10*52  w2^T [i][k][o52]
#define B2P 19192      // 52
#define W3P 19248      // 50*100*12  w3 [i][o][k12]
#define W4P 79248      // 100*200*12 w4 [i][o][k12]
#define P1  319248     // 256*25*330
#define P2  2431248    // 256*50*108 (rows padded 107->108)
#define P3  3813648    // 256*100*32
#define P4  4632848    // 256*1400
#define PREP_N 319248
// ---------------------------------------------------------------------------

__device__ __forceinline__ float elu1(float v) {
    return v > 0.f ? v : __expf(v) - 1.f;
}
__device__ __forceinline__ float max3(float a, float b, float c) {
    return fmaxf(fmaxf(a, b), c);
}

// ---- K0: weight prep ------------------------------------------------------
__global__ __launch_bounds__(256) void k_prep(
    const float* __restrict__ wt, const float* __restrict__ bt,
    const float* __restrict__ wsp, const float* __restrict__ bsp,
    const float* __restrict__ w2, const float* __restrict__ b2,
    const float* __restrict__ w3, const float* __restrict__ w4,
    float* __restrict__ ws) {
    int idx = blockIdx.x * 256 + threadIdx.x;
    if (idx < 6160) {                       // WCT [c][k][o28]
        int c = idx / 280, r = idx % 280;
        int k = r / 28, o = r % 28;
        float s = 0.f;
        if (o < 25)
            for (int i = 0; i < 25; ++i) s += wt[i * 10 + k] * wsp[(o * 25 + i) * 22 + c];
        ws[WCT + idx] = s;
    } else if (idx < 6188) {                // BCP
        int o = idx - 6160;
        float s = 0.f;
        if (o < 25) {
            s = bsp[o];
            for (int i = 0; i < 25; ++i) {
                float rs = 0.f;
                for (int c = 0; c < 22; ++c) rs += wsp[(o * 25 + i) * 22 + c];
                s += bt[i] * rs;
            }
        }
        ws[BCP + o] = s;
    } else if (idx >= W2T && idx < W2T + 13000) {
        int j = idx - W2T;
        int i = j / 520, r = j % 520, k = r / 52, o = r % 52;
        ws[idx] = (o < 50) ? w2[(o * 25 + i) * 10 + k] : 0.f;
    } else if (idx >= B2P && idx < B2P + 52) {
        int o = idx - B2P;
        ws[idx] = (o < 50) ? b2[o] : 0.f;
    } else if (idx >= W3P && idx < W3P + 60000) {
        int j = idx - W3P;
        int i = j / 1200, r = j % 1200, o = r / 12, k = r % 12;
        ws[idx] = (k < 10) ? w3[(o * 50 + i) * 10 + k] : 0.f;
    } else if (idx >= W4P && idx < W4P + 240000) {
        int j = idx - W4P;
        int i = j / 2400, r = j % 2400, o = r / 12, k = r % 12;
        ws[idx] = (k < 10) ? w4[(o * 100 + i) * 10 + k] : 0.f;
    }
}

// ---- K1: combined conv + ELU + pool3 -> p1[b][25][330] --------------------
// block = (b, tc3), 448 thr = 7 og-waves; lanes = tpg (55 active).
__global__ __launch_bounds__(448, 4) void k_conv12(
    const float* __restrict__ x, const float* __restrict__ wct,
    const float* __restrict__ bcp, float* __restrict__ p1) {
    int b = blockIdx.x / 3, tc = blockIdx.x % 3;
    __shared__ float xs[22 * 340];
    int tid = threadIdx.x;
    int t0 = tc * 330;
    for (int idx = tid; idx < 22 * 339; idx += 448) {
        int c = idx / 339, t = idx - c * 339;
        xs[c * 340 + t] = x[b * 22000 + c * 1000 + t0 + t];
    }
    __syncthreads();

    int og = __builtin_amdgcn_readfirstlane((int)(threadIdx.x >> 6));
    int o0 = og * 4;
    int lane = tid & 63;
    bool act = lane < 55;
    int tpg = act ? lane : 54;
    int tl = tpg * 6;

    float4 bv = *reinterpret_cast<const float4*>(bcp + o0);   // s_load
    float acc[4][6];
#pragma unroll
    for (int j = 0; j < 6; ++j) {
        acc[0][j] = bv.x; acc[1][j] = bv.y; acc[2][j] = bv.z; acc[3][j] = bv.w;
    }
    for (int c = 0; c < 22; ++c) {
        float xv[15];
        const float* xr = xs + c * 340 + tl;
#pragma unroll
        for (int q = 0; q < 15; ++q) xv[q] = xr[q];
        const float* wp = wct + c * 280 + o0;                 // scalar addr
#pragma unroll
        for (int k = 0; k < 10; ++k) {
            float4 w = *reinterpret_cast<const float4*>(wp + k * 28);  // s_load
#pragma unroll
            for (int j = 0; j < 6; ++j) {
                float xx = xv[j + k];
                acc[0][j] = fmaf(xx, w.x, acc[0][j]);
                acc[1][j] = fmaf(xx, w.y, acc[1][j]);
                acc[2][j] = fmaf(xx, w.z, acc[2][j]);
                acc[3][j] = fmaf(xx, w.w, acc[3][j]);
            }
        }
    }
    if (act) {
        int tp0 = (tc * 55 + tpg) * 2;
#pragma unroll
        for (int oo = 0; oo < 4; ++oo) {
            if (o0 + oo < 25) {
                float2 st;
                st.x = elu1(max3(acc[oo][0], acc[oo][1], acc[oo][2]));
                st.y = elu1(max3(acc[oo][3], acc[oo][4], acc[oo][5]));
                *reinterpret_cast<float2*>(p1 + (b * 25 + o0 + oo) * 330 + tp0) = st;
            }
        }
    }
}

// ---- K2: conv3 + ELU + pool -> p2[b][50][108] -----------------------------
// block = (b, oghalf), 448 thr = 7 og-waves; lanes = tpg (54 active).
__global__ __launch_bounds__(448, 4) void k_conv3(
    const float* __restrict__ p1, const float* __restrict__ w2t,
    const float* __restrict__ b2p, float* __restrict__ p2) {
    int b = blockIdx.x >> 1, half = blockIdx.x & 1;
    __shared__ float xs[25 * 332];
    int tid = threadIdx.x;
    for (int idx = tid; idx < 8250; idx += 448) {
        int i = idx / 330, t = idx - i * 330;
        xs[i * 332 + t] = p1[b * 8250 + idx];
    }
    __syncthreads();

    int og = __builtin_amdgcn_readfirstlane((int)(threadIdx.x >> 6)) + half * 7;
    if (og >= 13) return;
    int o0 = og * 4;
    int lane = tid & 63;
    bool act = lane < 54;
    int tpg = act ? lane : 53;
    int tl = tpg * 6;

    float4 bv = *reinterpret_cast<const float4*>(b2p + o0);
    float acc[4][6];
#pragma unroll
    for (int j = 0; j < 6; ++j) {
        acc[0][j] = bv.x; acc[1][j] = bv.y; acc[2][j] = bv.z; acc[3][j] = bv.w;
    }
    for (int i = 0; i < 25; ++i) {
        float xv[15];
        const float* xr = xs + i * 332 + tl;
#pragma unroll
        for (int q = 0; q < 15; ++q) xv[q] = xr[q];
        const float* wp = w2t + i * 520 + o0;
#pragma unroll
        for (int k = 0; k < 10; ++k) {
            float4 w = *reinterpret_cast<const float4*>(wp + k * 52);
#pragma unroll
            for (int j = 0; j < 6; ++j) {
                float xx = xv[j + k];
                acc[0][j] = fmaf(xx, w.x, acc[0][j]);
                acc[1][j] = fmaf(xx, w.y, acc[1][j]);
                acc[2][j] = fmaf(xx, w.z, acc[2][j]);
                acc[3][j] = fmaf(xx, w.w, acc[3][j]);
            }
        }
    }
    if (act) {
        int tp0 = tpg * 2;
#pragma unroll
        for (int oo = 0; oo < 4; ++oo) {
            int o = o0 + oo;
            if (o < 50) {
                float* orow = p2 + (b * 50 + o) * 108;
                float e0 = elu1(max3(acc[oo][0], acc[oo][1], acc[oo][2]));
                if (tp0 + 1 < 107) {
                    float2 st; st.x = e0;
                    st.y = elu1(max3(acc[oo][3], acc[oo][4], acc[oo][5]));
                    *reinterpret_cast<float2*>(orow + tp0) = st;
                } else {
                    orow[tp0] = e0;
                }
            }
        }
    }
}

// ---- K3: conv4 + ELU + pool -> p3[b][100][32] -----------------------------
// block = (b, tpc4), 512 thr = 8 waves = 2 o-waves x 4 i-quarters.
// lane -> o; x broadcast from LDS; weights [i][o][k12] per-lane coalesced.
__global__ __launch_bounds__(512, 6) void k_conv4(
    const float* __restrict__ p2, const float* __restrict__ w3p,
    const float* __restrict__ b3, float* __restrict__ p3) {
    int b = blockIdx.x >> 2, tpc = blockIdx.x & 3;
    __shared__ float xs[50 * 36];
    __shared__ float red[3 * 100 * 24];
    int tid = threadIdx.x;
    int t0 = tpc * 24;
    for (int idx = tid; idx < 50 * 33; idx += 512) {
        int i = idx / 33, t = idx - i * 33;
        xs[i * 36 + t] = p2[(b * 50 + i) * 108 + t0 + t];
    }
    __syncthreads();

    int w = tid >> 6, lane = tid & 63;
    int ow = w & 1, iq = w >> 1;
    int ol = ow * 64 + lane;
    bool act = ol < 100;
    int oc = act ? ol : 99;

    float acc[24];
#pragma unroll
    for (int j = 0; j < 24; ++j) acc[j] = 0.f;

    for (int i = iq; i < 50; i += 4) {
        const float* wp = w3p + i * 1200 + oc * 12;
        float4 wa = *reinterpret_cast<const float4*>(wp);
        float4 wb = *reinterpret_cast<const float4*>(wp + 4);
        float2 wc = *reinterpret_cast<const float2*>(wp + 8);
        float wv[10] = {wa.x, wa.y, wa.z, wa.w, wb.x, wb.y, wb.z, wb.w, wc.x, wc.y};
        const float* xr = xs + i * 36;
#pragma unroll
        for (int q = 0; q < 9; ++q) {
            float4 xq = *reinterpret_cast<const float4*>(xr + 4 * q);
            float xe[4] = {xq.x, xq.y, xq.z, xq.w};
#pragma unroll
            for (int e = 0; e < 4; ++e) {
                int s = 4 * q + e;
#pragma unroll
                for (int k = 0; k < 10; ++k) {
                    int j = s - k;
                    if (j >= 0 && j < 24) acc[j] = fmaf(xe[e], wv[k], acc[j]);
                }
            }
        }
    }
    if (iq > 0) {
        if (act) {
            float* rr = red + ((iq - 1) * 100 + ol) * 24;
#pragma unroll
            for (int j = 0; j < 24; ++j) rr[j] = acc[j];
        }
    }
    __syncthreads();
    if (iq == 0 && act) {
#pragma unroll
        for (int p = 0; p < 3; ++p) {
            const float* rr = red + (p * 100 + ol) * 24;
#pragma unroll
            for (int j = 0; j < 24; ++j) acc[j] += rr[j];
        }
        float bb = b3[ol];
        float ov[8];
#pragma unroll
        for (int q = 0; q < 8; ++q)
            ov[q] = elu1(max3(acc[3 * q], acc[3 * q + 1], acc[3 * q + 2]) + bb);
        float* orow = p3 + (b * 100 + ol) * 32 + tpc * 8;
        *reinterpret_cast<float4*>(orow) = make_float4(ov[0], ov[1], ov[2], ov[3]);
        *reinterpret_cast<float4*>(orow + 4) = make_float4(ov[4], ov[5], ov[6], ov[7]);
    }
}

// ---- K4: conv5 + ELU + pool -> p4[b][1400] --------------------------------
// block = (b, ohalf), 512 thr = 8 waves = 2 o-waves x 4 i-quarters.
__global__ __launch_bounds__(512, 6) void k_conv5(
    const float* __restrict__ p3, const float* __restrict__ w4p,
    const float* __restrict__ b4, float* __restrict__ p4) {
    int b = blockIdx.x >> 1, oh = blockIdx.x & 1;
    __shared__ float xs[100 * 32];
    __shared__ float red[3 * 100 * 21];
    int tid = threadIdx.x;
    for (int idx = tid; idx < 800; idx += 512) {
        reinterpret_cast<float4*>(xs)[idx] =
            reinterpret_cast<const float4*>(p3 + b * 3200)[idx];
    }
    __syncthreads();

    int w = tid >> 6, lane = tid & 63;
    int ow = w & 1, iq = w >> 1;
    int ol = ow * 64 + lane;
    bool act = ol < 100;
    int oc = act ? ol : 99;
    int o = oh * 100 + oc;

    float acc[21];
#pragma unroll
    for (int j = 0; j < 21; ++j) acc[j] = 0.f;

    for (int i = iq; i < 100; i += 4) {
        const float* wp = w4p + i * 2400 + o * 12;
        float4 wa = *reinterpret_cast<const float4*>(wp);
        float4 wb = *reinterpret_cast<const float4*>(wp + 4);
        float2 wc = *reinterpret_cast<const float2*>(wp + 8);
        float wv[10] = {wa.x, wa.y, wa.z, wa.w, wb.x, wb.y, wb.z, wb.w, wc.x, wc.y};
        const float* xr = xs + i * 32;
#pragma unroll
        for (int q = 0; q < 8; ++q) {
            float4 xq = *reinterpret_cast<const float4*>(xr + 4 * q);
            float xe[4] = {xq.x, xq.y, xq.z, xq.w};
#pragma unroll
            for (int e = 0; e < 4; ++e) {
                int s = 4 * q + e;
#pragma unroll
                for (int k = 0; k < 10; ++k) {
                    int j = s - k;
                    if (j >= 0 && j < 21) acc[j] = fmaf(xe[e], wv[k], acc[j]);
                }
            }
        }
    }
    if (iq > 0) {
        if (act) {
            float* rr = red + ((iq - 1) * 100 + ol) * 21;
#pragma unroll
            for (int j = 0; j < 21; ++j) rr[j] = acc[j];
        }
    }
    __syncthreads();
    if (iq == 0 && act) {
#pragma unroll
        for (int p = 0; p < 3; ++p) {
            const float* rr = red + (p * 100 + ol) * 21;
#pragma unroll
            for (int j = 0; j < 21; ++j) acc[j] += rr[j];
        }
        float bb = b4[o];
        float* pr = p4 + b * 1400 + o * 7;
#pragma unroll
        for (int tp = 0; tp < 7; ++tp)
            pr[tp] = elu1(max3(acc[3 * tp], acc[3 * tp + 1], acc[3 * tp + 2]) + bb);
    }
}

// ---- K5: per-sample head, one wave per output -----------------------------
__global__ __launch_bounds__(256) void k_head(const float* __restrict__ hW,
                                              const float* __restrict__ hB,
                                              const int* __restrict__ sid,
                                              const float* __restrict__ p4,
                                              float* __restrict__ out) {
    int b = blockIdx.x;
    int tid = threadIdx.x;
    int wave = tid >> 6, lane = tid & 63;
    const float* feat = p4 + b * 1400;
    int sidb = sid[b];
    const float* wrow = hW + (sidb * 4 + wave) * 1400;
    float acc = 0.f;
    for (int f = lane; f < 1400; f += 64) acc += wrow[f] * feat[f];
#pragma unroll
    for (int off = 32; off; off >>= 1) acc += __shfl_down(acc, off);
    if (lane == 0) out[b * 4 + wave] = acc + hB[sidb * 4 + wave];
}

extern "C" void kernel_launch(void* const* d_in, const int* in_sizes, int n_in,
                              void* d_out, int out_size, void* d_ws, size_t ws_size,
                              hipStream_t stream) {
    const float* x   = (const float*)d_in[0];
    const int*   sid = (const int*)d_in[1];
    const float* wt  = (const float*)d_in[2];
    const float* bt  = (const float*)d_in[3];
    const float* wsp = (const float*)d_in[4];
    const float* bsp = (const float*)d_in[5];
    const float* w2  = (const float*)d_in[6];
    const float* b2  = (const float*)d_in[7];
    const float* w3  = (const float*)d_in[8];
    const float* b3  = (const float*)d_in[9];
    const float* w4  = (const float*)d_in[10];
    const float* b4  = (const float*)d_in[11];
    const float* hW  = (const float*)d_in[12];
    const float* hB  = (const float*)d_in[13];
    float* out = (float*)d_out;
    float* ws  = (float*)d_ws;

    k_prep<<<(PREP_N + 255) / 256, 256, 0, stream>>>(wt, bt, wsp, bsp, w2, b2, w3, w4, ws);
    k_conv12<<<768, 448, 0, stream>>>(x, ws + WCT, ws + BCP, ws + P1);
    k_conv3<<<512, 448, 0, stream>>>(ws + P1, ws + W2T, ws + B2P, ws + P2);
    k_conv4<<<1024, 512, 0, stream>>>(ws + P2, ws + W3P, b3, ws + P3);
    k_conv5<<<512, 512, 0, stream>>>(ws + P3, ws + W4P, b4, ws + P4);
    k_head<<<256, 256, 0, stream>>>(hW, hB, sid, ws + P4, out);
}

// Round 5
// 254.231 us; speedup vs baseline: 1.6598x; 1.0120x over previous
//
#include <hip/hip_runtime.h>
#include <math.h>

// ---------------------------------------------------------------------------
// Deep4Net, fp32. conv1+conv2 fused algebraically; pool(elu)=elu(pool).
// conv12/conv3: wave-uniform (scalar) weights in per-wave-contiguous layout
//               [og][c|i][k][oo4] -> batched s_load_dwordx16; lanes = time;
//               x staged in LDS, read as float2 (b64).
// conv4/conv5:  lanes = output channel, weights [i][o][k-pad12] per-lane 48B
//               coalesced loads with manual i+4 double-buffer prefetch;
//               x staged in LDS, broadcast float4 reads; i split 4-way across
//               waves with LDS partial reduce.
//
// Workspace (float offsets):
#define WCT 0          // 7*22*10*4 = 6160   Wc [og][c][k][oo4]
#define BCP 6160       // 28
#define W2T 6192       // 13*25*10*4 = 13000 w2 [og][i][k][oo4]
#define B2P 19192      // 52
#define W3P 19248      // 50*100*12  w3 [i][o][k12]
#define W4P 79248      // 100*200*12 w4 [i][o][k12]
#define P1  319248     // 256*25*330
#define P2  2431248    // 256*50*108 (rows padded 107->108)
#define P3  3813648    // 256*100*32
#define P4  4632848    // 256*1400
#define PREP_N 319248
// ---------------------------------------------------------------------------

__device__ __forceinline__ float elu1(float v) {
    return v > 0.f ? v : __expf(v) - 1.f;
}
__device__ __forceinline__ float max3(float a, float b, float c) {
    return fmaxf(fmaxf(a, b), c);
}

// ---- K0: weight prep ------------------------------------------------------
__global__ __launch_bounds__(256) void k_prep(
    const float* __restrict__ wt, const float* __restrict__ bt,
    const float* __restrict__ wsp, const float* __restrict__ bsp,
    const float* __restrict__ w2, const float* __restrict__ b2,
    const float* __restrict__ w3, const float* __restrict__ w4,
    float* __restrict__ ws) {
    int idx = blockIdx.x * 256 + threadIdx.x;
    if (idx < 6160) {                       // WCT [og][c][k][oo4]
        int og = idx / 880, r = idx % 880;
        int c = r / 40, r2 = r % 40;
        int k = r2 / 4, oo = r2 % 4;
        int o = og * 4 + oo;
        float s = 0.f;
        if (o < 25)
            for (int i = 0; i < 25; ++i) s += wt[i * 10 + k] * wsp[(o * 25 + i) * 22 + c];
        ws[WCT + idx] = s;
    } else if (idx < 6188) {                // BCP
        int o = idx - 6160;
        float s = 0.f;
        if (o < 25) {
            s = bsp[o];
            for (int i = 0; i < 25; ++i) {
                float rs = 0.f;
                for (int c = 0; c < 22; ++c) rs += wsp[(o * 25 + i) * 22 + c];
                s += bt[i] * rs;
            }
        }
        ws[BCP + o] = s;
    } else if (idx >= W2T && idx < W2T + 13000) {   // [og][i][k][oo4]
        int j = idx - W2T;
        int og = j / 1000, r = j % 1000;
        int i = r / 40, r2 = r % 40;
        int k = r2 / 4, oo = r2 % 4;
        int o = og * 4 + oo;
        ws[idx] = (o < 50) ? w2[(o * 25 + i) * 10 + k] : 0.f;
    } else if (idx >= B2P && idx < B2P + 52) {
        int o = idx - B2P;
        ws[idx] = (o < 50) ? b2[o] : 0.f;
    } else if (idx >= W3P && idx < W3P + 60000) {
        int j = idx - W3P;
        int i = j / 1200, r = j % 1200, o = r / 12, k = r % 12;
        ws[idx] = (k < 10) ? w3[(o * 50 + i) * 10 + k] : 0.f;
    } else if (idx >= W4P && idx < W4P + 240000) {
        int j = idx - W4P;
        int i = j / 2400, r = j % 2400, o = r / 12, k = r % 12;
        ws[idx] = (k < 10) ? w4[(o * 100 + i) * 10 + k] : 0.f;
    }
}

// ---- K1: combined conv + ELU + pool3 -> p1[b][25][330] --------------------
// block = (b, tc3), 448 thr = 7 og-waves; lanes = tpg (55 active).
__global__ __launch_bounds__(448, 4) void k_conv12(
    const float* __restrict__ x, const float* __restrict__ wct,
    const float* __restrict__ bcp, float* __restrict__ p1) {
    int b = blockIdx.x / 3, tc = blockIdx.x % 3;
    __shared__ float xs[22 * 340];
    int tid = threadIdx.x;
    int t0 = tc * 330;
    for (int idx = tid; idx < 22 * 339; idx += 448) {
        int c = idx / 339, t = idx - c * 339;
        xs[c * 340 + t] = x[b * 22000 + c * 1000 + t0 + t];
    }
    __syncthreads();

    int og = __builtin_amdgcn_readfirstlane((int)(threadIdx.x >> 6));
    int o0 = og * 4;
    int lane = tid & 63;
    bool act = lane < 55;
    int tpg = act ? lane : 54;
    int tl = tpg * 6;

    float4 bv = *reinterpret_cast<const float4*>(bcp + o0);   // s_load
    float acc[4][6];
#pragma unroll
    for (int j = 0; j < 6; ++j) {
        acc[0][j] = bv.x; acc[1][j] = bv.y; acc[2][j] = bv.z; acc[3][j] = bv.w;
    }
    const float* wbase = wct + og * 880;                      // wave-uniform
#pragma unroll 2
    for (int c = 0; c < 22; ++c) {
        float xv[15];
        const float* xr = xs + c * 340 + tl;
        const float2* xp2 = reinterpret_cast<const float2*>(xr);
#pragma unroll
        for (int q = 0; q < 7; ++q) { float2 v = xp2[q]; xv[2 * q] = v.x; xv[2 * q + 1] = v.y; }
        xv[14] = xr[14];
        const float4* wp = reinterpret_cast<const float4*>(wbase + c * 40);
#pragma unroll
        for (int k = 0; k < 10; ++k) {
            float4 w = wp[k];                                 // contiguous s_load
#pragma unroll
            for (int j = 0; j < 6; ++j) {
                float xx = xv[j + k];
                acc[0][j] = fmaf(xx, w.x, acc[0][j]);
                acc[1][j] = fmaf(xx, w.y, acc[1][j]);
                acc[2][j] = fmaf(xx, w.z, acc[2][j]);
                acc[3][j] = fmaf(xx, w.w, acc[3][j]);
            }
        }
    }
    if (act) {
        int tp0 = (tc * 55 + tpg) * 2;
#pragma unroll
        for (int oo = 0; oo < 4; ++oo) {
            if (o0 + oo < 25) {
                float2 st;
                st.x = elu1(max3(acc[oo][0], acc[oo][1], acc[oo][2]));
                st.y = elu1(max3(acc[oo][3], acc[oo][4], acc[oo][5]));
                *reinterpret_cast<float2*>(p1 + (b * 25 + o0 + oo) * 330 + tp0) = st;
            }
        }
    }
}

// ---- K2: conv3 + ELU + pool -> p2[b][50][108] -----------------------------
// block = (b, oghalf), 448 thr = 7 og-waves; lanes = tpg (54 active).
__global__ __launch_bounds__(448, 4) void k_conv3(
    const float* __restrict__ p1, const float* __restrict__ w2t,
    const float* __restrict__ b2p, float* __restrict__ p2) {
    int b = blockIdx.x >> 1, half = blockIdx.x & 1;
    __shared__ float xs[25 * 332 + 8];
    int tid = threadIdx.x;
    for (int idx = tid; idx < 8250; idx += 448) {
        int i = idx / 330, t = idx - i * 330;
        xs[i * 332 + t] = p1[b * 8250 + idx];
    }
    __syncthreads();

    int og = __builtin_amdgcn_readfirstlane((int)(threadIdx.x >> 6)) + half * 7;
    if (og >= 13) return;
    int o0 = og * 4;
    int lane = tid & 63;
    bool act = lane < 54;
    int tpg = act ? lane : 53;
    int tl = tpg * 6;

    float4 bv = *reinterpret_cast<const float4*>(b2p + o0);
    float acc[4][6];
#pragma unroll
    for (int j = 0; j < 6; ++j) {
        acc[0][j] = bv.x; acc[1][j] = bv.y; acc[2][j] = bv.z; acc[3][j] = bv.w;
    }
    const float* wbase = w2t + og * 1000;
#pragma unroll 2
    for (int i = 0; i < 25; ++i) {
        float xv[15];
        const float* xr = xs + i * 332 + tl;
        const float2* xp2 = reinterpret_cast<const float2*>(xr);
#pragma unroll
        for (int q = 0; q < 7; ++q) { float2 v = xp2[q]; xv[2 * q] = v.x; xv[2 * q + 1] = v.y; }
        xv[14] = xr[14];
        const float4* wp = reinterpret_cast<const float4*>(wbase + i * 40);
#pragma unroll
        for (int k = 0; k < 10; ++k) {
            float4 w = wp[k];
#pragma unroll
            for (int j = 0; j < 6; ++j) {
                float xx = xv[j + k];
                acc[0][j] = fmaf(xx, w.x, acc[0][j]);
                acc[1][j] = fmaf(xx, w.y, acc[1][j]);
                acc[2][j] = fmaf(xx, w.z, acc[2][j]);
                acc[3][j] = fmaf(xx, w.w, acc[3][j]);
            }
        }
    }
    if (act) {
        int tp0 = tpg * 2;
#pragma unroll
        for (int oo = 0; oo < 4; ++oo) {
            int o = o0 + oo;
            if (o < 50) {
                float* orow = p2 + (b * 50 + o) * 108;
                float e0 = elu1(max3(acc[oo][0], acc[oo][1], acc[oo][2]));
                if (tp0 + 1 < 107) {
                    float2 st; st.x = e0;
                    st.y = elu1(max3(acc[oo][3], acc[oo][4], acc[oo][5]));
                    *reinterpret_cast<float2*>(orow + tp0) = st;
                } else {
                    orow[tp0] = e0;
                }
            }
        }
    }
}

// ---- K3: conv4 + ELU + pool -> p3[b][100][32] -----------------------------
// block = (b, tpc4), 512 thr = 2 o-waves x 4 i-quarters; weight prefetch.
__global__ __launch_bounds__(512, 4) void k_conv4(
    const float* __restrict__ p2, const float* __restrict__ w3p,
    const float* __restrict__ b3, float* __restrict__ p3) {
    int b = blockIdx.x >> 2, tpc = blockIdx.x & 3;
    __shared__ float xs[50 * 36];
    __shared__ float red[3 * 100 * 24];
    int tid = threadIdx.x;
    int t0 = tpc * 24;
    for (int idx = tid; idx < 50 * 33; idx += 512) {
        int i = idx / 33, t = idx - i * 33;
        xs[i * 36 + t] = p2[(b * 50 + i) * 108 + t0 + t];
    }
    __syncthreads();

    int w = tid >> 6, lane = tid & 63;
    int ow = w & 1, iq = w >> 1;
    int ol = ow * 64 + lane;
    bool act = ol < 100;
    int oc = act ? ol : 99;

    float acc[24];
#pragma unroll
    for (int j = 0; j < 24; ++j) acc[j] = 0.f;

    const float* wp0 = w3p + iq * 1200 + oc * 12;
    float4 wa = *reinterpret_cast<const float4*>(wp0);
    float4 wb = *reinterpret_cast<const float4*>(wp0 + 4);
    float2 wc2 = *reinterpret_cast<const float2*>(wp0 + 8);

    for (int i = iq; i < 50; i += 4) {
        int inext = (i + 4 < 50) ? i + 4 : i;
        const float* np = w3p + inext * 1200 + oc * 12;
        float4 na = *reinterpret_cast<const float4*>(np);
        float4 nb = *reinterpret_cast<const float4*>(np + 4);
        float2 nc2 = *reinterpret_cast<const float2*>(np + 8);

        float wv[10] = {wa.x, wa.y, wa.z, wa.w, wb.x, wb.y, wb.z, wb.w, wc2.x, wc2.y};
        const float* xr = xs + i * 36;
#pragma unroll
        for (int q = 0; q < 9; ++q) {
            float4 xq = *reinterpret_cast<const float4*>(xr + 4 * q);
            float xe[4] = {xq.x, xq.y, xq.z, xq.w};
#pragma unroll
            for (int e = 0; e < 4; ++e) {
                int s = 4 * q + e;
#pragma unroll
                for (int k = 0; k < 10; ++k) {
                    int j = s - k;
                    if (j >= 0 && j < 24) acc[j] = fmaf(xe[e], wv[k], acc[j]);
                }
            }
        }
        wa = na; wb = nb; wc2 = nc2;
    }
    if (iq > 0 && act) {
        float* rr = red + ((iq - 1) * 100 + ol) * 24;
#pragma unroll
        for (int j = 0; j < 24; ++j) rr[j] = acc[j];
    }
    __syncthreads();
    if (iq == 0 && act) {
#pragma unroll
        for (int p = 0; p < 3; ++p) {
            const float* rr = red + (p * 100 + ol) * 24;
#pragma unroll
            for (int j = 0; j < 24; ++j) acc[j] += rr[j];
        }
        float bb = b3[ol];
        float ov[8];
#pragma unroll
        for (int q = 0; q < 8; ++q)
            ov[q] = elu1(max3(acc[3 * q], acc[3 * q + 1], acc[3 * q + 2]) + bb);
        float* orow = p3 + (b * 100 + ol) * 32 + tpc * 8;
        *reinterpret_cast<float4*>(orow) = make_float4(ov[0], ov[1], ov[2], ov[3]);
        *reinterpret_cast<float4*>(orow + 4) = make_float4(ov[4], ov[5], ov[6], ov[7]);
    }
}

// ---- K4: conv5 + ELU + pool -> p4[b][1400] --------------------------------
// block = (b, ohalf), 512 thr = 2 o-waves x 4 i-quarters; weight prefetch.
__global__ __launch_bounds__(512, 4) void k_conv5(
    const float* __restrict__ p3, const float* __restrict__ w4p,
    const float* __restrict__ b4, float* __restrict__ p4) {
    int b = blockIdx.x >> 1, oh = blockIdx.x & 1;
    __shared__ float xs[100 * 32];
    __shared__ float red[3 * 100 * 21];
    int tid = threadIdx.x;
    for (int idx = tid; idx < 800; idx += 512) {
        reinterpret_cast<float4*>(xs)[idx] =
            reinterpret_cast<const float4*>(p3 + b * 3200)[idx];
    }
    __syncthreads();

    int w = tid >> 6, lane = tid & 63;
    int ow = w & 1, iq = w >> 1;
    int ol = ow * 64 + lane;
    bool act = ol < 100;
    int oc = act ? ol : 99;
    int o = oh * 100 + oc;

    float acc[21];
#pragma unroll
    for (int j = 0; j < 21; ++j) acc[j] = 0.f;

    const float* wp0 = w4p + iq * 2400 + o * 12;
    float4 wa = *reinterpret_cast<const float4*>(wp0);
    float4 wb = *reinterpret_cast<const float4*>(wp0 + 4);
    float2 wc2 = *reinterpret_cast<const float2*>(wp0 + 8);

    for (int i = iq; i < 100; i += 4) {
        int inext = (i + 4 < 100) ? i + 4 : i;
        const float* np = w4p + inext * 2400 + o * 12;
        float4 na = *reinterpret_cast<const float4*>(np);
        float4 nb = *reinterpret_cast<const float4*>(np + 4);
        float2 nc2 = *reinterpret_cast<const float2*>(np + 8);

        float wv[10] = {wa.x, wa.y, wa.z, wa.w, wb.x, wb.y, wb.z, wb.w, wc2.x, wc2.y};
        const float* xr = xs + i * 32;
#pragma unroll
        for (int q = 0; q < 8; ++q) {
            float4 xq = *reinterpret_cast<const float4*>(xr + 4 * q);
            float xe[4] = {xq.x, xq.y, xq.z, xq.w};
#pragma unroll
            for (int e = 0; e < 4; ++e) {
                int s = 4 * q + e;
#pragma unroll
                for (int k = 0; k < 10; ++k) {
                    int j = s - k;
                    if (j >= 0 && j < 21) acc[j] = fmaf(xe[e], wv[k], acc[j]);
                }
            }
        }
        wa = na; wb = nb; wc2 = nc2;
    }
    if (iq > 0 && act) {
        float* rr = red + ((iq - 1) * 100 + ol) * 21;
#pragma unroll
        for (int j = 0; j < 21; ++j) rr[j] = acc[j];
    }
    __syncthreads();
    if (iq == 0 && act) {
#pragma unroll
        for (int p = 0; p < 3; ++p) {
            const float* rr = red + (p * 100 + ol) * 21;
#pragma unroll
            for (int j = 0; j < 21; ++j) acc[j] += rr[j];
        }
        float bb = b4[o];
        float* pr = p4 + b * 1400 + o * 7;
#pragma unroll
        for (int tp = 0; tp < 7; ++tp)
            pr[tp] = elu1(max3(acc[3 * tp], acc[3 * tp + 1], acc[3 * tp + 2]) + bb);
    }
}

// ---- K5: per-sample head, one wave per output, float4 dot -----------------
__global__ __launch_bounds__(256) void k_head(const float* __restrict__ hW,
                                              const float* __restrict__ hB,
                                              const int* __restrict__ sid,
                                              const float* __restrict__ p4,
                                              float* __restrict__ out) {
    int b = blockIdx.x;
    int tid = threadIdx.x;
    int wave = tid >> 6, lane = tid & 63;
    int sidb = sid[b];
    const float4* wrow = reinterpret_cast<const float4*>(hW + (sidb * 4 + wave) * 1400);
    const float4* feat = reinterpret_cast<const float4*>(p4 + b * 1400);
    float acc = 0.f;
    for (int f = lane; f < 350; f += 64) {
        float4 a = wrow[f], c = feat[f];
        acc += a.x * c.x + a.y * c.y + a.z * c.z + a.w * c.w;
    }
#pragma unroll
    for (int off = 32; off; off >>= 1) acc += __shfl_down(acc, off);
    if (lane == 0) out[b * 4 + wave] = acc + hB[sidb * 4 + wave];
}

extern "C" void kernel_launch(void* const* d_in, const int* in_sizes, int n_in,
                              void* d_out, int out_size, void* d_ws, size_t ws_size,
                              hipStream_t stream) {
    const float* x   = (const float*)d_in[0];
    const int*   sid = (const int*)d_in[1];
    const float* wt  = (const float*)d_in[2];
    const float* bt  = (const float*)d_in[3];
    const float* wsp = (const float*)d_in[4];
    const float* bsp = (const float*)d_in[5];
    const float* w2  = (const float*)d_in[6];
    const float* b2  = (const float*)d_in[7];
    const float* w3  = (const float*)d_in[8];
    const float* b3  = (const float*)d_in[9];
    const float* w4  = (const float*)d_in[10];
    const float* b4  = (const float*)d_in[11];
    const float* hW  = (const float*)d_in[12];
    const float* hB  = (const float*)d_in[13];
    float* out = (float*)d_out;
    float* ws  = (float*)d_ws;

    k_prep<<<(PREP_N + 255) / 256, 256, 0, stream>>>(wt, bt, wsp, bsp, w2, b2, w3, w4, ws);
    k_conv12<<<768, 448, 0, stream>>>(x, ws + WCT, ws + BCP, ws + P1);
    k_conv3<<<512, 448, 0, stream>>>(ws + P1, ws + W2T, ws + B2P, ws + P2);
    k_conv4<<<1024, 512, 0, stream>>>(ws + P2, ws + W3P, b3, ws + P3);
    k_conv5<<<512, 512, 0, stream>>>(ws + P3, ws + W4P, b4, ws + P4);
    k_head<<<256, 256, 0, stream>>>(hW, hB, sid, ws + P4, out);
}

// Round 6
// 193.944 us; speedup vs baseline: 2.1758x; 1.3108x over previous
//
#include <hip/hip_runtime.h>
#include <math.h>

// ---------------------------------------------------------------------------
// Deep4Net via bf16 MFMA (fp32 accum). conv1+conv2 fused algebraically;
// pool(elu)=elu(pool). Each K=10 conv = 10 accumulated GEMMs over channels:
//   out[o][t] += sum_i wk[k][o][i] * xT[t+k][i]
// Activations stored time-major (xT[t][iPad]) in bf16 so both MFMA fragments
// are single aligned 16B loads:
//   A-frag: wk[k][o=lane&15 (+tile)][i: quad*8..+7]   (global, L2-hot)
//   B-frag: xT[t= tile + lane&15 + k][i: quad*8..+7]  (LDS ds_read_b128)
// Epilogue: C frags -> LDS f32 -> pool3+ELU+bias -> bf16 transposed store.
//
// Workspace: float region then short(bf16) region.
#define F_BC   0         // 32   combined bias (padded)
#define F_B2   32        // 64
#define F_B3   96        // 128
#define F_B4   224       // 224
#define F_P4   448       // 256*1400 f32 features
#define SHORT_BASE 717696  // short index of bf16 region ( = 1,435,392 bytes /2 )
#define WK12   0         // [10][32][32]
#define WK3    10240     // [10][64][32]
#define WK4    30720     // [10][128][64]
#define WK5    112640    // [10][224][128]
#define P1T    399360    // [256][330][32]
#define P2T    3102720   // [256][107][64]
#define P3T    4855808   // [256][32][128]
// ---------------------------------------------------------------------------

typedef __attribute__((ext_vector_type(8))) short short8;
typedef __attribute__((ext_vector_type(4))) float f32x4;

__device__ __forceinline__ short f2bf(float f) {
    union { float f; unsigned u; } v; v.f = f;
    unsigned r = v.u + 0x7FFF + ((v.u >> 16) & 1);
    return (short)(r >> 16);
}

// ---- K0: weight prep (combine conv1/2, transpose+pad all to bf16) ---------
__global__ __launch_bounds__(256) void k_prep2(
    const float* __restrict__ wt, const float* __restrict__ bt,
    const float* __restrict__ wsp, const float* __restrict__ bsp,
    const float* __restrict__ w2, const float* __restrict__ b2,
    const float* __restrict__ w3, const float* __restrict__ b3,
    const float* __restrict__ w4, const float* __restrict__ b4,
    float* __restrict__ wsf, short* __restrict__ wss) {
    int idx = blockIdx.x * 256 + threadIdx.x;
    if (idx < 448) {                           // padded biases (f32)
        float v = 0.f;
        if (idx < 32) {
            int o = idx;
            if (o < 25) {
                v = bsp[o];
                for (int i = 0; i < 25; ++i) {
                    float rs = 0.f;
                    for (int c = 0; c < 22; ++c) rs += wsp[(o * 25 + i) * 22 + c];
                    v += bt[i] * rs;
                }
            }
        } else if (idx < 96)  { int o = idx - 32;  v = (o < 50)  ? b2[o] : 0.f; }
        else if (idx < 224)   { int o = idx - 96;  v = (o < 100) ? b3[o] : 0.f; }
        else                  { int o = idx - 224; v = (o < 200) ? b4[o] : 0.f; }
        wsf[idx] = v;
        return;
    }
    int j = idx - 448;
    if (j < 10240) {                           // wk12 [k][32][32] (combined)
        int k = j / 1024, o = (j / 32) % 32, i = j % 32;
        float v = 0.f;
        if (o < 25 && i < 22)
            for (int q = 0; q < 25; ++q) v += wt[q * 10 + k] * wsp[(o * 25 + q) * 22 + i];
        wss[WK12 + j] = f2bf(v);
        return;
    }
    j -= 10240;
    if (j < 20480) {                           // wk3 [k][64][32]
        int k = j / 2048, o = (j / 32) % 64, i = j % 32;
        float v = (o < 50 && i < 25) ? w2[(o * 25 + i) * 10 + k] : 0.f;
        wss[WK3 + j] = f2bf(v);
        return;
    }
    j -= 20480;
    if (j < 81920) {                           // wk4 [k][128][64]
        int k = j / 8192, o = (j / 64) % 128, i = j % 64;
        float v = (o < 100 && i < 50) ? w3[(o * 50 + i) * 10 + k] : 0.f;
        wss[WK4 + j] = f2bf(v);
        return;
    }
    j -= 81920;
    if (j < 286720) {                          // wk5 [k][224][128]
        int k = j / 28672, o = (j / 128) % 224, i = j % 128;
        float v = (o < 200 && i < 100) ? w4[(o * 100 + i) * 10 + k] : 0.f;
        wss[WK5 + j] = f2bf(v);
    }
}

// ---- generic MFMA conv+pool+ELU layer -------------------------------------
// block = 4 waves: wave w -> (m-tile w%WM, n-group w/WM of NT 16-wide tiles)
// grid: idx = b + 256*(nc + NC*mc)
template<int OPAD, int IPAD, int IB, int WM, int NT, int NCHUNK, bool F32IN, bool LAST>
__global__ __launch_bounds__(256) void k_cmfma(
    const short* __restrict__ wk, const float* __restrict__ bias,
    const short* __restrict__ xinT, const float* __restrict__ xf32,
    short* __restrict__ outT, float* __restrict__ p4,
    int NC, int TIN, int NPtot) {
    constexpr int ROWS = NCHUNK + 9;
    constexpr int MSPAN = WM * 16;
    __shared__ short xs[ROWS * IPAD];
    __shared__ float sc[MSPAN * NCHUNK];

    int idx = blockIdx.x;
    int b = idx % 256;
    int nc = (idx / 256) % NC;
    int mc = idx / (256 * NC);
    int t0 = nc * NCHUNK;
    int tid = threadIdx.x;

    // ---- stage input tile into LDS (bf16, time-major) ----
    if constexpr (F32IN) {
        // x[b][c][t] f32 -> xs[r*32 + c]; pad c>=22 with 0
        const float* xb = xf32 + b * 22000;
        for (int i = tid; i < 32 * 128; i += 256) {
            int c = i >> 7, r = i & 127;
            if (r < ROWS) {
                short v = 0;
                if (c < 22) {
                    int t = t0 + r; if (t > 999) t = 999;
                    v = f2bf(xb[c * 1000 + t]);
                }
                xs[r * IPAD + c] = v;
            }
        }
    } else {
        const short* xb = xinT + (size_t)b * TIN * IPAD;
        constexpr int V = IPAD / 8;
        for (int i = tid; i < ROWS * V; i += 256) {
            int r = i / V, vv = i - r * V;
            int t = t0 + r; if (t >= TIN) t = TIN - 1;   // clamp; extras discarded
            *(short8*)(xs + r * IPAD + vv * 8) =
                *(const short8*)(xb + (size_t)t * IPAD + vv * 8);
        }
    }
    __syncthreads();

    int w = tid >> 6, lane = tid & 63, l15 = lane & 15, quad = lane >> 4;
    int mt = w % WM, ns = w / WM;
    int orow = mc * MSPAN + mt * 16 + l15;
    int tw = ns * NT * 16;

    f32x4 acc[NT];
#pragma unroll
    for (int i = 0; i < NT; ++i) acc[i] = (f32x4){0.f, 0.f, 0.f, 0.f};

    const short* wbase = wk + (size_t)orow * IPAD + quad * 8;
#pragma unroll 2
    for (int k = 0; k < 10; ++k) {
#pragma unroll
        for (int ib = 0; ib < IB; ++ib) {
            short8 a = *(const short8*)(wbase + (size_t)k * OPAD * IPAD + ib * 32);
#pragma unroll
            for (int nt = 0; nt < NT; ++nt) {
                short8 bf = *(const short8*)(xs + (tw + nt * 16 + l15 + k) * IPAD +
                                             ib * 32 + quad * 8);
                acc[nt] = __builtin_amdgcn_mfma_f32_16x16x32_bf16(a, bf, acc[nt], 0, 0, 0);
            }
        }
    }

    // ---- C frags -> LDS f32 scratch [o_local][t_local] ----
#pragma unroll
    for (int nt = 0; nt < NT; ++nt) {
        int col = tw + nt * 16 + l15;
        int rbase = mt * 16 + quad * 4;
#pragma unroll
        for (int r = 0; r < 4; ++r)
            sc[(rbase + r) * NCHUNK + col] = acc[nt][r];
    }
    __syncthreads();

    // ---- pool3 + bias + ELU + store (bf16 transposed, or f32 feats) ----
    constexpr int PC = NCHUNK / 3;
    int pc0 = nc * PC;
    for (int i = tid; i < PC * MSPAN; i += 256) {
        int tp = i / MSPAN, ol = i - tp * MSPAN;
        if (pc0 + tp < NPtot) {
            const float* s = sc + ol * NCHUNK + tp * 3;
            float m = fmaxf(fmaxf(s[0], s[1]), s[2]) + bias[mc * MSPAN + ol];
            float e = m > 0.f ? m : __expf(m) - 1.f;
            if constexpr (LAST) {
                int o = mc * MSPAN + ol;
                if (o < 200) p4[(size_t)b * 1400 + o * 7 + (pc0 + tp)] = e;
            } else {
                outT[(size_t)b * NPtot * OPAD + (size_t)(pc0 + tp) * OPAD +
                     mc * MSPAN + ol] = f2bf(e);
            }
        }
    }
}

// ---- head: per-sample routed linear, one wave per output, f32 -------------
__global__ __launch_bounds__(256) void k_head(const float* __restrict__ hW,
                                              const float* __restrict__ hB,
                                              const int* __restrict__ sid,
                                              const float* __restrict__ p4,
                                              float* __restrict__ out) {
    int b = blockIdx.x;
    int tid = threadIdx.x;
    int wave = tid >> 6, lane = tid & 63;
    int sidb = sid[b];
    const float4* wrow = reinterpret_cast<const float4*>(hW + (sidb * 4 + wave) * 1400);
    const float4* feat = reinterpret_cast<const float4*>(p4 + b * 1400);
    float acc = 0.f;
    for (int f = lane; f < 350; f += 64) {
        float4 a = wrow[f], c = feat[f];
        acc += a.x * c.x + a.y * c.y + a.z * c.z + a.w * c.w;
    }
#pragma unroll
    for (int off = 32; off; off >>= 1) acc += __shfl_down(acc, off);
    if (lane == 0) out[b * 4 + wave] = acc + hB[sidb * 4 + wave];
}

extern "C" void kernel_launch(void* const* d_in, const int* in_sizes, int n_in,
                              void* d_out, int out_size, void* d_ws, size_t ws_size,
                              hipStream_t stream) {
    const float* x   = (const float*)d_in[0];
    const int*   sid = (const int*)d_in[1];
    const float* wt  = (const float*)d_in[2];
    const float* bt  = (const float*)d_in[3];
    const float* wsp = (const float*)d_in[4];
    const float* bsp = (const float*)d_in[5];
    const float* w2  = (const float*)d_in[6];
    const float* b2  = (const float*)d_in[7];
    const float* w3  = (const float*)d_in[8];
    const float* b3  = (const float*)d_in[9];
    const float* w4  = (const float*)d_in[10];
    const float* b4  = (const float*)d_in[11];
    const float* hW  = (const float*)d_in[12];
    const float* hB  = (const float*)d_in[13];
    float* out = (float*)d_out;
    float* wsf = (float*)d_ws;
    short* wss = (short*)d_ws + SHORT_BASE;

    // prep: 448 + 10240 + 20480 + 81920 + 286720 = 399808 elements
    k_prep2<<<1562, 256, 0, stream>>>(wt, bt, wsp, bsp, w2, b2, w3, b3, w4, b4,
                                      wsf, wss);
    // conv12: M=32(25), N=990 unpooled -> 330 pooled; 11 n-chunks of 96
    k_cmfma<32, 32, 1, 2, 3, 96, true, false><<<256 * 11, 256, 0, stream>>>(
        wss + WK12, wsf + F_BC, nullptr, x, wss + P1T, nullptr, 11, 1000, 330);
    // conv3: M=64(50), 107 pooled; 7 n-chunks of 48
    k_cmfma<64, 32, 1, 4, 3, 48, false, false><<<256 * 7, 256, 0, stream>>>(
        wss + WK3, wsf + F_B2, wss + P1T, nullptr, wss + P2T, nullptr, 7, 330, 107);
    // conv4: M=128(100) in 2 m-chunks, 32 pooled; 2 n-chunks of 48
    k_cmfma<128, 64, 2, 4, 3, 48, false, false><<<256 * 2 * 2, 256, 0, stream>>>(
        wss + WK4, wsf + F_B3, wss + P2T, nullptr, wss + P3T, nullptr, 2, 107, 32);
    // conv5: M=224(200) in 7 m-chunks, 7 pooled; 1 n-chunk of 32
    k_cmfma<224, 128, 4, 2, 1, 32, false, true><<<256 * 7, 256, 0, stream>>>(
        wss + WK5, wsf + F_B4, wss + P3T, nullptr, nullptr, wsf + F_P4, 1, 32, 7);
    k_head<<<256, 256, 0, stream>>>(hW, hB, sid, wsf + F_P4, out);
}

// Round 7
// 174.755 us; speedup vs baseline: 2.4147x; 1.1098x over previous
//
#include <hip/hip_runtime.h>
#include <math.h>

// ---------------------------------------------------------------------------
// Deep4Net via bf16 MFMA (fp32 accum). conv1+conv2 fused algebraically;
// pool(elu)=elu(pool). Each K=10 conv = 10 accumulated GEMMs over channels:
//   out[o][t] += sum_i wk[k][o][i] * xT[t+k][i]
// Activations stored time-major (xT[t][iPad]) in bf16 so both MFMA fragments
// are single aligned 16B loads:
//   A-frag: wk[k][o=lane&15 (+tile)][i: quad*8..+7]   (global, L2-hot)
//   B-frag: xT[t= tile + lane&15 + k][i: quad*8..+7]  (LDS ds_read_b128)
// LDS anti-conflict: xs rows padded +4 shorts (stride 18/18/34/66 dwords,
// <=2-way); epilogue scratch sc stored transposed [col][o] with odd stride
// MSPAN+1 (conflict-free for both C-frag writes and pooled reads).
//
// Workspace: float region then short(bf16) region.
#define F_BC   0         // 32   combined bias (padded)
#define F_B2   32        // 64
#define F_B3   96        // 128
#define F_B4   224       // 224
#define F_P4   448       // 256*1400 f32 features
#define SHORT_BASE 717696  // short index of bf16 region
#define WK12   0         // [10][32][32]
#define WK3    10240     // [10][64][32]
#define WK4    30720     // [10][128][64]
#define WK5    112640    // [10][224][128]
#define P1T    399360    // [256][330][32]
#define P2T    3102720   // [256][107][64]
#define P3T    4855808   // [256][32][128]
// ---------------------------------------------------------------------------

typedef __attribute__((ext_vector_type(8))) short short8;
typedef __attribute__((ext_vector_type(4))) float f32x4;

__device__ __forceinline__ short f2bf(float f) {
    union { float f; unsigned u; } v; v.f = f;
    unsigned r = v.u + 0x7FFF + ((v.u >> 16) & 1);
    return (short)(r >> 16);
}

// ---- K0: weight prep (combine conv1/2, transpose+pad all to bf16) ---------
__global__ __launch_bounds__(256) void k_prep2(
    const float* __restrict__ wt, const float* __restrict__ bt,
    const float* __restrict__ wsp, const float* __restrict__ bsp,
    const float* __restrict__ w2, const float* __restrict__ b2,
    const float* __restrict__ w3, const float* __restrict__ b3,
    const float* __restrict__ w4, const float* __restrict__ b4,
    float* __restrict__ wsf, short* __restrict__ wss) {
    int idx = blockIdx.x * 256 + threadIdx.x;
    if (idx < 448) {                           // padded biases (f32)
        float v = 0.f;
        if (idx < 32) {
            int o = idx;
            if (o < 25) {
                v = bsp[o];
                for (int i = 0; i < 25; ++i) {
                    float rs = 0.f;
                    for (int c = 0; c < 22; ++c) rs += wsp[(o * 25 + i) * 22 + c];
                    v += bt[i] * rs;
                }
            }
        } else if (idx < 96)  { int o = idx - 32;  v = (o < 50)  ? b2[o] : 0.f; }
        else if (idx < 224)   { int o = idx - 96;  v = (o < 100) ? b3[o] : 0.f; }
        else                  { int o = idx - 224; v = (o < 200) ? b4[o] : 0.f; }
        wsf[idx] = v;
        return;
    }
    int j = idx - 448;
    if (j < 10240) {                           // wk12 [k][32][32] (combined)
        int k = j / 1024, o = (j / 32) % 32, i = j % 32;
        float v = 0.f;
        if (o < 25 && i < 22)
            for (int q = 0; q < 25; ++q) v += wt[q * 10 + k] * wsp[(o * 25 + q) * 22 + i];
        wss[WK12 + j] = f2bf(v);
        return;
    }
    j -= 10240;
    if (j < 20480) {                           // wk3 [k][64][32]
        int k = j / 2048, o = (j / 32) % 64, i = j % 32;
        float v = (o < 50 && i < 25) ? w2[(o * 25 + i) * 10 + k] : 0.f;
        wss[WK3 + j] = f2bf(v);
        return;
    }
    j -= 20480;
    if (j < 81920) {                           // wk4 [k][128][64]
        int k = j / 8192, o = (j / 64) % 128, i = j % 64;
        float v = (o < 100 && i < 50) ? w3[(o * 50 + i) * 10 + k] : 0.f;
        wss[WK4 + j] = f2bf(v);
        return;
    }
    j -= 81920;
    if (j < 286720) {                          // wk5 [k][224][128]
        int k = j / 28672, o = (j / 128) % 224, i = j % 128;
        float v = (o < 200 && i < 100) ? w4[(o * 100 + i) * 10 + k] : 0.f;
        wss[WK5 + j] = f2bf(v);
    }
}

// ---- generic MFMA conv+pool+ELU layer -------------------------------------
// block = 4 waves: wave w -> (m-tile w%WM, n-group w/WM of NT 16-wide tiles)
// grid: idx = b + 256*(nc + NC*mc)
template<int OPAD, int IPAD, int IB, int WM, int NT, int NCHUNK, bool F32IN, bool LAST>
__global__ __launch_bounds__(256) void k_cmfma(
    const short* __restrict__ wk, const float* __restrict__ bias,
    const short* __restrict__ xinT, const float* __restrict__ xf32,
    short* __restrict__ outT, float* __restrict__ p4,
    int NC, int TIN, int NPtot) {
    constexpr int ROWS = NCHUNK + 9;
    constexpr int MSPAN = WM * 16;
    constexpr int XSTR = IPAD + 4;      // +4 shorts: bank-conflict-free rows
    constexpr int SSTR = MSPAN + 1;     // odd stride: conflict-free sc
    __shared__ short xs[ROWS * XSTR];
    __shared__ float sc[NCHUNK * SSTR];

    int idx = blockIdx.x;
    int b = idx % 256;
    int nc = (idx / 256) % NC;
    int mc = idx / (256 * NC);
    int t0 = nc * NCHUNK;
    int tid = threadIdx.x;

    // ---- stage input tile into LDS (bf16, time-major) ----
    if constexpr (F32IN) {
        // x[b][c][t] f32 -> xs[r*XSTR + c]; pad c>=22 with 0
        const float* xb = xf32 + b * 22000;
        for (int i = tid; i < 32 * 128; i += 256) {
            int c = i >> 7, r = i & 127;
            if (r < ROWS) {
                short v = 0;
                if (c < 22) {
                    int t = t0 + r; if (t > 999) t = 999;
                    v = f2bf(xb[c * 1000 + t]);
                }
                xs[r * XSTR + c] = v;
            }
        }
    } else {
        const short* xb = xinT + (size_t)b * TIN * IPAD;
        constexpr int V = IPAD / 8;
        for (int i = tid; i < ROWS * V; i += 256) {
            int r = i / V, vv = i - r * V;
            int t = t0 + r; if (t >= TIN) t = TIN - 1;   // clamp; extras discarded
            *(short8*)(xs + r * XSTR + vv * 8) =
                *(const short8*)(xb + (size_t)t * IPAD + vv * 8);
        }
    }
    __syncthreads();

    int w = tid >> 6, lane = tid & 63, l15 = lane & 15, quad = lane >> 4;
    int mt = w % WM, ns = w / WM;
    int orow = mc * MSPAN + mt * 16 + l15;
    int tw = ns * NT * 16;

    f32x4 acc[NT];
#pragma unroll
    for (int i = 0; i < NT; ++i) acc[i] = (f32x4){0.f, 0.f, 0.f, 0.f};

    const short* wbase = wk + (size_t)orow * IPAD + quad * 8;
#pragma unroll 2
    for (int k = 0; k < 10; ++k) {
#pragma unroll
        for (int ib = 0; ib < IB; ++ib) {
            short8 a = *(const short8*)(wbase + (size_t)k * OPAD * IPAD + ib * 32);
#pragma unroll
            for (int nt = 0; nt < NT; ++nt) {
                short8 bf = *(const short8*)(xs + (tw + nt * 16 + l15 + k) * XSTR +
                                             ib * 32 + quad * 8);
                acc[nt] = __builtin_amdgcn_mfma_f32_16x16x32_bf16(a, bf, acc[nt], 0, 0, 0);
            }
        }
    }

    // ---- C frags -> LDS f32 scratch, transposed: sc[col][o_local] ----
#pragma unroll
    for (int nt = 0; nt < NT; ++nt) {
        int col = tw + nt * 16 + l15;
        int rbase = mt * 16 + quad * 4;
#pragma unroll
        for (int r = 0; r < 4; ++r)
            sc[col * SSTR + rbase + r] = acc[nt][r];
    }
    __syncthreads();

    // ---- pool3 + bias + ELU + store (bf16 transposed, or f32 feats) ----
    constexpr int PC = NCHUNK / 3;
    int pc0 = nc * PC;
    for (int i = tid; i < PC * MSPAN; i += 256) {
        int tp = i / MSPAN, ol = i - tp * MSPAN;
        if (pc0 + tp < NPtot) {
            float s0 = sc[(tp * 3 + 0) * SSTR + ol];
            float s1 = sc[(tp * 3 + 1) * SSTR + ol];
            float s2 = sc[(tp * 3 + 2) * SSTR + ol];
            float m = fmaxf(fmaxf(s0, s1), s2) + bias[mc * MSPAN + ol];
            float e = m > 0.f ? m : __expf(m) - 1.f;
            if constexpr (LAST) {
                int o = mc * MSPAN + ol;
                if (o < 200) p4[(size_t)b * 1400 + o * 7 + (pc0 + tp)] = e;
            } else {
                outT[(size_t)b * NPtot * OPAD + (size_t)(pc0 + tp) * OPAD +
                     mc * MSPAN + ol] = f2bf(e);
            }
        }
    }
}

// ---- head: per-sample routed linear, one wave per output, f32 -------------
__global__ __launch_bounds__(256) void k_head(const float* __restrict__ hW,
                                              const float* __restrict__ hB,
                                              const int* __restrict__ sid,
                                              const float* __restrict__ p4,
                                              float* __restrict__ out) {
    int b = blockIdx.x;
    int tid = threadIdx.x;
    int wave = tid >> 6, lane = tid & 63;
    int sidb = sid[b];
    const float4* wrow = reinterpret_cast<const float4*>(hW + (sidb * 4 + wave) * 1400);
    const float4* feat = reinterpret_cast<const float4*>(p4 + b * 1400);
    float acc = 0.f;
    for (int f = lane; f < 350; f += 64) {
        float4 a = wrow[f], c = feat[f];
        acc += a.x * c.x + a.y * c.y + a.z * c.z + a.w * c.w;
    }
#pragma unroll
    for (int off = 32; off; off >>= 1) acc += __shfl_down(acc, off);
    if (lane == 0) out[b * 4 + wave] = acc + hB[sidb * 4 + wave];
}

extern "C" void kernel_launch(void* const* d_in, const int* in_sizes, int n_in,
                              void* d_out, int out_size, void* d_ws, size_t ws_size,
                              hipStream_t stream) {
    const float* x   = (const float*)d_in[0];
    const int*   sid = (const int*)d_in[1];
    const float* wt  = (const float*)d_in[2];
    const float* bt  = (const float*)d_in[3];
    const float* wsp = (const float*)d_in[4];
    const float* bsp = (const float*)d_in[5];
    const float* w2  = (const float*)d_in[6];
    const float* b2  = (const float*)d_in[7];
    const float* w3  = (const float*)d_in[8];
    const float* b3  = (const float*)d_in[9];
    const float* w4  = (const float*)d_in[10];
    const float* b4  = (const float*)d_in[11];
    const float* hW  = (const float*)d_in[12];
    const float* hB  = (const float*)d_in[13];
    float* out = (float*)d_out;
    float* wsf = (float*)d_ws;
    short* wss = (short*)d_ws + SHORT_BASE;

    // prep: 448 + 10240 + 20480 + 81920 + 286720 = 399808 elements
    k_prep2<<<1562, 256, 0, stream>>>(wt, bt, wsp, bsp, w2, b2, w3, b3, w4, b4,
                                      wsf, wss);
    // conv12: M=32(25), N=990 unpooled -> 330 pooled; 11 n-chunks of 96
    k_cmfma<32, 32, 1, 2, 3, 96, true, false><<<256 * 11, 256, 0, stream>>>(
        wss + WK12, wsf + F_BC, nullptr, x, wss + P1T, nullptr, 11, 1000, 330);
    // conv3: M=64(50), 107 pooled; 7 n-chunks of 48
    k_cmfma<64, 32, 1, 4, 3, 48, false, false><<<256 * 7, 256, 0, stream>>>(
        wss + WK3, wsf + F_B2, wss + P1T, nullptr, wss + P2T, nullptr, 7, 330, 107);
    // conv4: M=128(100) in 2 m-chunks, 32 pooled; 2 n-chunks of 48
    k_cmfma<128, 64, 2, 4, 3, 48, false, false><<<256 * 2 * 2, 256, 0, stream>>>(
        wss + WK4, wsf + F_B3, wss + P2T, nullptr, wss + P3T, nullptr, 2, 107, 32);
    // conv5: M=224(200) in 7 m-chunks, 7 pooled; 1 n-chunk of 32
    k_cmfma<224, 128, 4, 2, 1, 32, false, true><<<256 * 7, 256, 0, stream>>>(
        wss + WK5, wsf + F_B4, wss + P3T, nullptr, nullptr, wsf + F_P4, 1, 32, 7);
    k_head<<<256, 256, 0, stream>>>(hW, hB, sid, wsf + F_P4, out);
}